// Round 9
// baseline (809.111 us; speedup 1.0000x reference)
//
#include <hip/hip_runtime.h>
#include <hip/hip_fp16.h>
#include <math.h>

constexpr int CH = 8;
constexpr int COLS = 25;

__device__ __forceinline__ unsigned packh2(float a, float b) {
    __half2 h = __floats2half2_rn(a, b);
    return *reinterpret_cast<unsigned*>(&h);
}
__device__ __forceinline__ float2 unpackh2(unsigned u) {
    __half2 h = *reinterpret_cast<__half2*>(&u);
    return __half22float2(h);
}

// ---------------- scan kernels (exclusive scan of [sizes1, sizes2]) ----------------
constexpr int SCAN_T = 256;
constexpr int SCAN_E = 16;
constexpr int SCAN_B = SCAN_T * SCAN_E;  // 4096

__global__ void k_block_sums(const int* __restrict__ s1, const int* __restrict__ s2,
                             int C1, int C2, int* __restrict__ blockSums) {
    __shared__ int sh[SCAN_T];
    const int L = C1 + C2;
    int base = blockIdx.x * SCAN_B + threadIdx.x * SCAN_E;
    int tot = 0;
    for (int j = 0; j < SCAN_E; ++j) {
        int g = base + j;
        if (g < L) tot += (g < C1) ? s1[g] : s2[g - C1];
    }
    sh[threadIdx.x] = tot;
    __syncthreads();
    for (int off = SCAN_T / 2; off > 0; off >>= 1) {
        if (threadIdx.x < off) sh[threadIdx.x] += sh[threadIdx.x + off];
        __syncthreads();
    }
    if (threadIdx.x == 0) blockSums[blockIdx.x] = sh[0];
}

__global__ void k_scan_block_sums(int* blockSums, int nb) {
    __shared__ int sh[256];
    int t = threadIdx.x;
    int v = (t < nb) ? blockSums[t] : 0;
    sh[t] = v;
    __syncthreads();
    for (int off = 1; off < 256; off <<= 1) {
        int w = (t >= off) ? sh[t - off] : 0;
        __syncthreads();
        sh[t] += w;
        __syncthreads();
    }
    if (t < nb) blockSums[t] = sh[t] - v;
}

__global__ void k_write_offsets(const int* __restrict__ s1, const int* __restrict__ s2,
                                const int* __restrict__ blockSums,
                                int C1, int C2, int* __restrict__ cur) {
    __shared__ int sh[SCAN_T];
    const int L = C1 + C2;
    int base = blockIdx.x * SCAN_B + threadIdx.x * SCAN_E;
    int pre[SCAN_E];
    int tot = 0;
    for (int j = 0; j < SCAN_E; ++j) {
        int g = base + j;
        pre[j] = tot;
        if (g < L) tot += (g < C1) ? s1[g] : s2[g - C1];
    }
    sh[threadIdx.x] = tot;
    __syncthreads();
    for (int off = 1; off < SCAN_T; off <<= 1) {
        int w = (threadIdx.x >= off) ? sh[threadIdx.x - off] : 0;
        __syncthreads();
        sh[threadIdx.x] += w;
        __syncthreads();
    }
    int texcl = sh[threadIdx.x] - tot;
    int bb = blockSums[blockIdx.x];
    for (int j = 0; j < SCAN_E; ++j) {
        int g = base + j;
        if (g < L) cur[g] = bb + texcl + pre[j];
    }
}

// ---- init: bucket cursors from cur0 boundaries; also set cur0[L] = 2N ----
__global__ void k_init_bcur(int* __restrict__ cur0, int* __restrict__ bcur,
                            int C1, int C2, int nb1, int nb2, int twoN) {
    int t = blockIdx.x * blockDim.x + threadIdx.x;
    if (t == 0) cur0[C1 + C2] = twoN;
    int NB2 = nb1 + nb2;
    if (t < NB2) {
        int lab0 = (t < nb1) ? (t << 9) : (C1 + ((t - nb1) << 7));
        bcur[t] = cur0[lab0];
    }
}

constexpr int NB_F = 800;   // >= 782 buckets per field

// =================== FAST PATH ===================
// pass A: data-carrying bin; labels in regs, rows loaded at scatter time
constexpr int FBT = 1024;
constexpr int FEPT = 32;
constexpr int FBE = FBT * FEPT;   // 32768 elements per chunk -> ~42-entry runs (672B)

__global__ __launch_bounds__(FBT) void k_binD2(
        const int* __restrict__ m1, const int* __restrict__ m2,
        const float* __restrict__ x,
        int* __restrict__ bcur1, int* __restrict__ bcur2,
        unsigned short* __restrict__ P, uint4* __restrict__ D, int N) {
    __shared__ int hist[NB_F];
    __shared__ int cnt[NB_F];
    const int c0 = blockIdx.x * FBE;
    int lab[FEPT];
    #pragma unroll
    for (int f = 0; f < 2; ++f) {
        const int* m = f ? m2 : m1;
        int* bc = f ? bcur2 : bcur1;
        const int shift = f ? 7 : 9;
        const int lmask = (1 << shift) - 1;
        for (int j = threadIdx.x; j < NB_F; j += FBT) hist[j] = 0;
        __syncthreads();
        #pragma unroll
        for (int k = 0; k < FEPT; ++k) {
            int g = c0 + k * FBT + threadIdx.x;   // coalesced
            lab[k] = (g < N) ? (m[g] - 1) : -1;
            if (lab[k] >= 0) atomicAdd(&hist[lab[k] >> shift], 1);
        }
        __syncthreads();
        for (int j = threadIdx.x; j < NB_F; j += FBT) {
            int h = hist[j];
            if (h > 0) cnt[j] = atomicAdd(&bc[j], h);
        }
        __syncthreads();
        #pragma unroll
        for (int k = 0; k < FEPT; ++k) {
            if (lab[k] >= 0) {
                int g = c0 + k * FBT + threadIdx.x;
                const float4* p = (const float4*)(x + (size_t)g * CH);  // coalesced, L2-hot on f=1
                float4 a = p[0], b = p[1];
                uint4 r;
                r.x = packh2(a.x, a.y);
                r.y = packh2(a.z, a.w);
                r.z = packh2(b.x, b.y);
                r.w = packh2(b.z, b.w);
                int pos = atomicAdd(&cnt[lab[k] >> shift], 1);
                P[pos] = (unsigned short)(lab[k] & lmask);
                D[pos] = r;
            }
        }
        __syncthreads();
    }
}

// pass B: per-bucket warm + LDS sort + uint2-per-lane register reduce (L2-local gather)
constexpr int ST = 1024;
constexpr int CAP = 12288;   // mean entries/bucket = 10737, sd ~104 -> 15 sigma

__global__ __launch_bounds__(ST) void k_sstatsD2(
        const unsigned short* __restrict__ P, const uint4* __restrict__ D,
        const int* __restrict__ cur0,
        const int* __restrict__ s1, const int* __restrict__ s2,
        float* __restrict__ out0, float* __restrict__ stats2,
        int C1, int C2, int nb1) {
    __shared__ int curs[512];
    __shared__ int sorted[CAP];   // 48KB -> 50KB total -> 2 blocks/CU (100% occ)
    int bkt = blockIdx.x;
    int lab0g, lab0loc, nlabs;
    const int* sz; float* outp;
    if (bkt < nb1) {
        lab0g = bkt << 9; lab0loc = lab0g;
        nlabs = min(512, C1 - lab0g); sz = s1; outp = out0;
    } else {
        int lb = (bkt - nb1) << 7; lab0g = C1 + lb; lab0loc = lb;
        nlabs = min(128, C2 - lb); sz = s2; outp = stats2;
    }
    const int s = cur0[lab0g];
    int count = cur0[lab0g + nlabs] - s;   // cur0[L]=2N set by k_init_bcur
    if (count > CAP) count = CAP;
    for (int j = threadIdx.x; j < nlabs; j += ST) curs[j] = cur0[lab0g + j] - s;
    __syncthreads();
    // warm the bucket's D region into L2 (coalesced)
    const uint2* Dw = (const uint2*)(D + s);
    for (int j = threadIdx.x; j < count * 2; j += ST) {
        uint2 w = Dw[j];
        asm volatile("" :: "v"(w.x), "v"(w.y));   // keep loads alive
    }
    // LDS counting sort of local entry ids by label
    for (int j = threadIdx.x; j < count; j += ST) {
        int lab = (int)P[s + j];
        int pos = atomicAdd(&curs[lab], 1);
        if (pos < CAP) sorted[pos] = j;
    }
    __syncthreads();

    const uint2* Dg = (const uint2*)D;
    const int chalf = threadIdx.x & 1;        // channel half: 0 -> ch0-3, 1 -> ch4-7
    if (bkt < nb1) {
        // field 1: 2 lanes per label (channel split, no cross-lane merge)
        const int group = threadIdx.x >> 1;   // 0..511
        for (int lab = group; lab < nlabs; lab += (ST >> 1)) {
            int n = sz[lab0loc + lab];
            int start = cur0[lab0g + lab] - s;
            int nn = n;
            if (start >= CAP) nn = 0;
            else if (start + nn > CAP) nn = CAP - start;   // guard (never hit)
            float mn[4] = {INFINITY, INFINITY, INFINITY, INFINITY};
            float mx[4] = {-INFINITY, -INFINITY, -INFINITY, -INFINITY};
            float sm[4] = {0.f, 0.f, 0.f, 0.f};
            const int nm1 = nn - 1;
            for (int j = 0; j < nn; j += 8) {
                uint2 u[8];
                #pragma unroll
                for (int k = 0; k < 8; ++k) {
                    int jj = j + k;
                    int jc = (jj < nn) ? jj : nm1;   // clamped -> always safe
                    int sid = sorted[start + jc];
                    u[k] = Dg[(size_t)(s + sid) * 2 + chalf];
                }
                #pragma unroll
                for (int k = 0; k < 8; ++k) {
                    bool ok = (j + k) < nn;
                    float2 f0 = unpackh2(u[k].x);
                    float2 f1 = unpackh2(u[k].y);
                    float v0 = ok ? f0.x : INFINITY, w0 = ok ? f0.x : -INFINITY;
                    float v1 = ok ? f0.y : INFINITY, w1 = ok ? f0.y : -INFINITY;
                    float v2 = ok ? f1.x : INFINITY, w2 = ok ? f1.x : -INFINITY;
                    float v3 = ok ? f1.y : INFINITY, w3 = ok ? f1.y : -INFINITY;
                    mn[0] = fminf(mn[0], v0); mx[0] = fmaxf(mx[0], w0); sm[0] += ok ? f0.x : 0.f;
                    mn[1] = fminf(mn[1], v1); mx[1] = fmaxf(mx[1], w1); sm[1] += ok ? f0.y : 0.f;
                    mn[2] = fminf(mn[2], v2); mx[2] = fmaxf(mx[2], w2); sm[2] += ok ? f1.x : 0.f;
                    mn[3] = fminf(mn[3], v3); mx[3] = fmaxf(mx[3], w3); sm[3] += ok ? f1.y : 0.f;
                }
            }
            float inv = 1.f / (float)n;
            float* row = outp + (size_t)(lab0loc + lab) * COLS;
            int cb = chalf * 4;
            #pragma unroll
            for (int i = 0; i < 4; ++i) {
                row[cb + i]      = mn[i];
                row[8 + cb + i]  = mx[i];
                row[16 + cb + i] = sm[i] * inv;
            }
            if (chalf == 0) row[24] = expf(-(float)n) - 0.5f;
        }
    } else {
        // field 2: 8 lanes per label = 4 element-quarters x 2 channel halves
        const int q = (threadIdx.x >> 1) & 3;
        const int group = threadIdx.x >> 3;   // 0..127
        for (int lab = group; lab < nlabs; lab += (ST >> 3)) {
            int n = sz[lab0loc + lab];
            int start = cur0[lab0g + lab] - s;
            int nn = n;
            if (start >= CAP) nn = 0;
            else if (start + nn > CAP) nn = CAP - start;
            const int myc = (nn - q + 3) >> 2;   // elements j with j%4==q
            float mn[4] = {INFINITY, INFINITY, INFINITY, INFINITY};
            float mx[4] = {-INFINITY, -INFINITY, -INFINITY, -INFINITY};
            float sm[4] = {0.f, 0.f, 0.f, 0.f};
            const int nm1 = nn - 1;
            for (int t = 0; t < myc; t += 8) {
                uint2 u[8];
                #pragma unroll
                for (int k = 0; k < 8; ++k) {
                    int tt = t + k;
                    int jj = q + 4 * tt;
                    int jc = (tt < myc) ? jj : nm1;
                    int sid = sorted[start + jc];
                    u[k] = Dg[(size_t)(s + sid) * 2 + chalf];
                }
                #pragma unroll
                for (int k = 0; k < 8; ++k) {
                    bool ok = (t + k) < myc;
                    float2 f0 = unpackh2(u[k].x);
                    float2 f1 = unpackh2(u[k].y);
                    mn[0] = fminf(mn[0], ok ? f0.x : INFINITY);
                    mx[0] = fmaxf(mx[0], ok ? f0.x : -INFINITY);
                    sm[0] += ok ? f0.x : 0.f;
                    mn[1] = fminf(mn[1], ok ? f0.y : INFINITY);
                    mx[1] = fmaxf(mx[1], ok ? f0.y : -INFINITY);
                    sm[1] += ok ? f0.y : 0.f;
                    mn[2] = fminf(mn[2], ok ? f1.x : INFINITY);
                    mx[2] = fmaxf(mx[2], ok ? f1.x : -INFINITY);
                    sm[2] += ok ? f1.x : 0.f;
                    mn[3] = fminf(mn[3], ok ? f1.y : INFINITY);
                    mx[3] = fmaxf(mx[3], ok ? f1.y : -INFINITY);
                    sm[3] += ok ? f1.y : 0.f;
                }
            }
            // merge the 4 element-quarters (xor tid bits 1,2 = q bits 0,1)
            #pragma unroll
            for (int i = 0; i < 4; ++i) {
                mn[i] = fminf(mn[i], __shfl_xor(mn[i], 2));
                mx[i] = fmaxf(mx[i], __shfl_xor(mx[i], 2));
                sm[i] += __shfl_xor(sm[i], 2);
                mn[i] = fminf(mn[i], __shfl_xor(mn[i], 4));
                mx[i] = fmaxf(mx[i], __shfl_xor(mx[i], 4));
                sm[i] += __shfl_xor(sm[i], 4);
            }
            if (q == 0) {
                float inv = 1.f / (float)n;
                float* row = outp + (size_t)(lab0loc + lab) * COLS;
                int cb = chalf * 4;
                #pragma unroll
                for (int i = 0; i < 4; ++i) {
                    row[cb + i]      = mn[i];
                    row[8 + cb + i]  = mx[i];
                    row[16 + cb + i] = sm[i] * inv;
                }
                if (chalf == 0) row[24] = expf(-(float)n) - 0.5f;
            }
        }
    }
}

// =================== FALLBACK (round-6 proven) ===================
constexpr int BT2 = 1024;
constexpr int EPT = 32;
constexpr int BE2 = BT2 * EPT;     // 32768

__global__ __launch_bounds__(BT2) void k_bin2(
        const int* __restrict__ m1, const int* __restrict__ m2,
        int* __restrict__ bcur1, int* __restrict__ bcur2,
        unsigned int* __restrict__ tmp, int N) {
    __shared__ int hist[NB_F];
    __shared__ int cnt[NB_F];
    const int c0 = blockIdx.x * BE2;
    int lab[EPT];
    #pragma unroll
    for (int f = 0; f < 2; ++f) {
        const int* m = f ? m2 : m1;
        int* bc = f ? bcur2 : bcur1;
        const int shift = f ? 7 : 9;
        const int lmask = (1 << shift) - 1;
        for (int j = threadIdx.x; j < NB_F; j += BT2) hist[j] = 0;
        __syncthreads();
        #pragma unroll
        for (int k = 0; k < EPT; ++k) {
            int g = c0 + k * BT2 + threadIdx.x;
            lab[k] = (g < N) ? (m[g] - 1) : -1;
            if (lab[k] >= 0) atomicAdd(&hist[lab[k] >> shift], 1);
        }
        __syncthreads();
        for (int j = threadIdx.x; j < NB_F; j += BT2) {
            int h = hist[j];
            if (h > 0) cnt[j] = atomicAdd(&bc[j], h);
        }
        __syncthreads();
        #pragma unroll
        for (int k = 0; k < EPT; ++k) {
            if (lab[k] >= 0) {
                int pos = atomicAdd(&cnt[lab[k] >> shift], 1);
                tmp[pos] = ((unsigned)(c0 + k * BT2 + threadIdx.x) << shift)
                         | (unsigned)(lab[k] & lmask);
            }
        }
        __syncthreads();
    }
}

__global__ __launch_bounds__(ST, 8) void k_sstats(
        const unsigned int* __restrict__ tmp, const int* __restrict__ cur0,
        const int* __restrict__ s1, const int* __restrict__ s2,
        const float* __restrict__ x,
        float* __restrict__ out0, float* __restrict__ stats2,
        int C1, int C2, int nb1) {
    __shared__ int curs[512];
    __shared__ int sorted[CAP];
    int bkt = blockIdx.x;
    int shift, lab0g, lab0loc, nlabs;
    const int* sz; float* outp;
    if (bkt < nb1) {
        shift = 9; lab0g = bkt << 9; lab0loc = lab0g;
        nlabs = min(512, C1 - lab0g); sz = s1; outp = out0;
    } else {
        shift = 7; int lb = (bkt - nb1) << 7; lab0g = C1 + lb; lab0loc = lb;
        nlabs = min(128, C2 - lb); sz = s2; outp = stats2;
    }
    const int lmask = (1 << shift) - 1;
    const int s = cur0[lab0g];
    int count = cur0[lab0g + nlabs] - s;
    if (count > CAP) count = CAP;
    for (int j = threadIdx.x; j < nlabs; j += ST) curs[j] = cur0[lab0g + j] - s;
    __syncthreads();
    for (int j = threadIdx.x; j < count; j += ST) {
        unsigned en = tmp[s + j];
        int lab = (int)(en & (unsigned)lmask);
        int pos = atomicAdd(&curs[lab], 1);
        if (pos < CAP) sorted[pos] = (int)(en >> shift);
    }
    __syncthreads();
    const int group = threadIdx.x >> 3;
    const int c = threadIdx.x & 7;
    for (int lab = group; lab < nlabs; lab += (ST >> 3)) {
        int n = sz[lab0loc + lab];
        int start = cur0[lab0g + lab] - s;
        int nn = n;
        if (start >= CAP) nn = 0;
        else if (start + nn > CAP) nn = CAP - start;
        float mn = INFINITY, mx = -INFINITY, sm = 0.f;
        const int nm1 = nn - 1;
        for (int j = 0; j < nn; j += 8) {
            float v[8];
            #pragma unroll
            for (int k = 0; k < 8; ++k) {
                int jj = j + k;
                int jc = (jj < nn) ? jj : nm1;
                int e = sorted[start + jc];
                v[k] = x[(size_t)e * CH + c];
            }
            #pragma unroll
            for (int k = 0; k < 8; ++k) {
                bool ok = (j + k) < nn;
                mn = fminf(mn, ok ? v[k] : INFINITY);
                mx = fmaxf(mx, ok ? v[k] : -INFINITY);
                sm += ok ? v[k] : 0.f;
            }
        }
        float* row = outp + (size_t)(lab0loc + lab) * COLS;
        row[c]      = mn;
        row[8 + c]  = mx;
        row[16 + c] = sm / (float)n;
        if (c == 0) row[24] = expf(-(float)n) - 0.5f;
    }
}

// ---------------- edge gather ----------------
__global__ void k_edges(const int* __restrict__ bounds, const float* __restrict__ stats2,
                        float* __restrict__ out1, float* __restrict__ out2, int C1) {
    int t = blockIdx.x * blockDim.x + threadIdx.x;
    int total = C1 * COLS;
    if (t >= 2 * total) return;
    int half = (t >= total) ? 1 : 0;
    int u = t - half * total;
    int e = u / COLS;
    int k = u - e * COLS;
    int node = bounds[e * 2 + half] - 1;
    float v = stats2[(size_t)node * COLS + k];
    (half ? out2 : out1)[u] = v;
}

extern "C" void kernel_launch(void* const* d_in, const int* in_sizes, int n_in,
                              void* d_out, int out_size, void* d_ws, size_t ws_size,
                              hipStream_t stream) {
    const float* x      = (const float*)d_in[0];
    const int*   m1     = (const int*)d_in[1];
    const int*   m2     = (const int*)d_in[2];
    const int*   bounds = (const int*)d_in[3];
    const int*   s1     = (const int*)d_in[4];
    const int*   s2     = (const int*)d_in[5];
    const int N  = in_sizes[1];
    const int C1 = in_sizes[4];
    const int C2 = in_sizes[5];
    const int L  = C1 + C2;
    const int nb1 = (C1 + 511) >> 9;   // 782
    const int nb2 = (C2 + 127) >> 7;   // 782
    const int nbk = nb1 + nb2;

    float* out0 = (float*)d_out;
    float* out1 = out0 + (size_t)C1 * COLS;
    float* out2 = out1 + (size_t)C1 * COLS;

    char* ws = (char*)d_ws;
    auto take = [&](size_t bytes) {
        char* p = ws;
        ws += (bytes + 255) & ~(size_t)255;
        return p;
    };

    const size_t dBytes = (size_t)2 * N * 16;   // 268 MB
    const size_t fastNeed = dBytes + (size_t)C2 * COLS * 4 + (size_t)nbk * 4 + 8192;
    const bool fast = (ws_size >= fastNeed) &&
                      ((size_t)2 * N * 2 <= (size_t)C1 * COLS * 4) &&   // P fits in out1
                      ((size_t)(L + 1) * 4 <= (size_t)C1 * COLS * 4);   // cur0 fits in out2

    const int nb = (L + SCAN_B - 1) / SCAN_B;   // 123 (<=256)

    if (fast) {
        uint4* D          = (uint4*)take(dBytes);
        float* stats2     = (float*)take((size_t)C2 * COLS * 4);
        int*   blockSums  = (int*)take(1024);
        int*   bcur       = (int*)take((size_t)nbk * 4);
        unsigned short* P = (unsigned short*)out1;   // dead before k_edges
        int*   cur0       = (int*)out2;              // dead before k_edges

        k_block_sums<<<nb, SCAN_T, 0, stream>>>(s1, s2, C1, C2, blockSums);
        k_scan_block_sums<<<1, 256, 0, stream>>>(blockSums, nb);
        k_write_offsets<<<nb, SCAN_T, 0, stream>>>(s1, s2, blockSums, C1, C2, cur0);
        k_init_bcur<<<(nbk + 255) / 256, 256, 0, stream>>>(cur0, bcur, C1, C2, nb1, nb2, 2 * N);

        const int binGrid = (N + FBE - 1) / FBE;   // 256
        k_binD2<<<binGrid, FBT, 0, stream>>>(m1, m2, x, bcur, bcur + nb1, P, D, N);

        k_sstatsD2<<<nbk, ST, 0, stream>>>(P, D, cur0, s1, s2, out0, stats2, C1, C2, nb1);

        int edge_threads = 2 * C1 * COLS;
        k_edges<<<(edge_threads + 255) / 256, 256, 0, stream>>>(bounds, stats2, out1, out2, C1);
    } else {
        int*   cur0      = (int*)  take((size_t)(L + 1) * 4);
        float* stats2    = (float*)take((size_t)C2 * COLS * 4);
        int*   blockSums = (int*)  take(1024);
        int*   bcur      = (int*)  take((size_t)nbk * 4);
        unsigned int* tmp = (unsigned int*)out1;   // 67MB in out1/out2 region

        k_block_sums<<<nb, SCAN_T, 0, stream>>>(s1, s2, C1, C2, blockSums);
        k_scan_block_sums<<<1, 256, 0, stream>>>(blockSums, nb);
        k_write_offsets<<<nb, SCAN_T, 0, stream>>>(s1, s2, blockSums, C1, C2, cur0);
        k_init_bcur<<<(nbk + 255) / 256, 256, 0, stream>>>(cur0, bcur, C1, C2, nb1, nb2, 2 * N);

        const int binGrid = (N + BE2 - 1) / BE2;   // 256
        k_bin2<<<binGrid, BT2, 0, stream>>>(m1, m2, bcur, bcur + nb1, tmp, N);

        k_sstats<<<nbk, ST, 0, stream>>>(tmp, cur0, s1, s2, x, out0, stats2, C1, C2, nb1);

        int edge_threads = 2 * C1 * COLS;
        k_edges<<<(edge_threads + 255) / 256, 256, 0, stream>>>(bounds, stats2, out1, out2, C1);
    }
}

// Round 10
// 506.846 us; speedup vs baseline: 1.5964x; 1.5964x over previous
//
#include <hip/hip_runtime.h>
#include <math.h>

constexpr int CH = 8;
constexpr int COLS = 25;

// ---------------- scan kernels (exclusive scan of [sizes1, sizes2]) ----------------
constexpr int SCAN_T = 256;
constexpr int SCAN_E = 16;
constexpr int SCAN_B = SCAN_T * SCAN_E;  // 4096

__global__ void k_block_sums(const int* __restrict__ s1, const int* __restrict__ s2,
                             int C1, int C2, int* __restrict__ blockSums) {
    __shared__ int sh[SCAN_T];
    const int L = C1 + C2;
    int base = blockIdx.x * SCAN_B + threadIdx.x * SCAN_E;
    int tot = 0;
    for (int j = 0; j < SCAN_E; ++j) {
        int g = base + j;
        if (g < L) tot += (g < C1) ? s1[g] : s2[g - C1];
    }
    sh[threadIdx.x] = tot;
    __syncthreads();
    for (int off = SCAN_T / 2; off > 0; off >>= 1) {
        if (threadIdx.x < off) sh[threadIdx.x] += sh[threadIdx.x + off];
        __syncthreads();
    }
    if (threadIdx.x == 0) blockSums[blockIdx.x] = sh[0];
}

__global__ void k_scan_block_sums(int* blockSums, int nb) {
    __shared__ int sh[256];
    int t = threadIdx.x;
    int v = (t < nb) ? blockSums[t] : 0;
    sh[t] = v;
    __syncthreads();
    for (int off = 1; off < 256; off <<= 1) {
        int w = (t >= off) ? sh[t - off] : 0;
        __syncthreads();
        sh[t] += w;
        __syncthreads();
    }
    if (t < nb) blockSums[t] = sh[t] - v;
}

__global__ void k_write_offsets(const int* __restrict__ s1, const int* __restrict__ s2,
                                const int* __restrict__ blockSums,
                                int C1, int C2, int* __restrict__ cur) {
    __shared__ int sh[SCAN_T];
    const int L = C1 + C2;
    int base = blockIdx.x * SCAN_B + threadIdx.x * SCAN_E;
    int pre[SCAN_E];
    int tot = 0;
    for (int j = 0; j < SCAN_E; ++j) {
        int g = base + j;
        pre[j] = tot;
        if (g < L) tot += (g < C1) ? s1[g] : s2[g - C1];
    }
    sh[threadIdx.x] = tot;
    __syncthreads();
    for (int off = 1; off < SCAN_T; off <<= 1) {
        int w = (threadIdx.x >= off) ? sh[threadIdx.x - off] : 0;
        __syncthreads();
        sh[threadIdx.x] += w;
        __syncthreads();
    }
    int texcl = sh[threadIdx.x] - tot;
    int bb = blockSums[blockIdx.x];
    for (int j = 0; j < SCAN_E; ++j) {
        int g = base + j;
        if (g < L) cur[g] = bb + texcl + pre[j];
    }
}

// ---- init: bucket cursors from cur0 boundaries; also set cur0[L] = 2N ----
__global__ void k_init_bcur(int* __restrict__ cur0, int* __restrict__ bcur,
                            int C1, int C2, int nb1, int nb2, int twoN) {
    int t = blockIdx.x * blockDim.x + threadIdx.x;
    if (t == 0) cur0[C1 + C2] = twoN;
    int NB2 = nb1 + nb2;
    if (t < NB2) {
        int lab0 = (t < nb1) ? (t << 9) : (C1 + ((t - nb1) << 7));
        bcur[t] = cur0[lab0];
    }
}

// ---------------- pass A: register-staged bin of both fields (round-6 proven) ----------------
constexpr int NB_F = 800;          // >= 782 buckets per field
constexpr int BT2 = 512;
constexpr int EPT = 16;            // elements per thread
constexpr int BE2 = BT2 * EPT;     // 8192 per chunk

__global__ __launch_bounds__(BT2) void k_bin2(
        const int* __restrict__ m1, const int* __restrict__ m2,
        int* __restrict__ bcur1, int* __restrict__ bcur2,
        unsigned int* __restrict__ tmp, int N) {
    __shared__ int hist[NB_F];
    __shared__ int cnt[NB_F];
    const int c0 = blockIdx.x * BE2;
    const int base = c0 + threadIdx.x * EPT;
    const bool full = (c0 + BE2 <= N);
    int lab[EPT];

    #pragma unroll
    for (int f = 0; f < 2; ++f) {
        const int* m = f ? m2 : m1;
        int* bc = f ? bcur2 : bcur1;
        const int shift = f ? 7 : 9;
        const int lmask = (1 << shift) - 1;
        for (int j = threadIdx.x; j < NB_F; j += BT2) hist[j] = 0;
        __syncthreads();
        if (full) {
            const int4* p = (const int4*)(m + base);
            int4 v0 = p[0], v1 = p[1], v2 = p[2], v3 = p[3];
            lab[0]=v0.x-1;  lab[1]=v0.y-1;  lab[2]=v0.z-1;  lab[3]=v0.w-1;
            lab[4]=v1.x-1;  lab[5]=v1.y-1;  lab[6]=v1.z-1;  lab[7]=v1.w-1;
            lab[8]=v2.x-1;  lab[9]=v2.y-1;  lab[10]=v2.z-1; lab[11]=v2.w-1;
            lab[12]=v3.x-1; lab[13]=v3.y-1; lab[14]=v3.z-1; lab[15]=v3.w-1;
        } else {
            #pragma unroll
            for (int k = 0; k < EPT; ++k) {
                int g = base + k;
                lab[k] = (g < N) ? (m[g] - 1) : -1;
            }
        }
        #pragma unroll
        for (int k = 0; k < EPT; ++k)
            if (lab[k] >= 0) atomicAdd(&hist[lab[k] >> shift], 1);
        __syncthreads();
        for (int j = threadIdx.x; j < NB_F; j += BT2) {
            int h = hist[j];
            if (h > 0) cnt[j] = atomicAdd(&bc[j], h);
        }
        __syncthreads();
        #pragma unroll
        for (int k = 0; k < EPT; ++k) {
            if (lab[k] >= 0) {
                int pos = atomicAdd(&cnt[lab[k] >> shift], 1);
                tmp[pos] = ((unsigned)(base + k) << shift) | (unsigned)(lab[k] & lmask);
            }
        }
        __syncthreads();
    }
}

// ---------------- per-bucket LDS sort + float2-per-lane register reduce ----------------
constexpr int ST = 1024;     // 16 waves/block, 2 blocks/CU
constexpr int CAP = 12288;   // mean entries/bucket = 10737, sd ~104 -> 15 sigma
constexpr int UNR = 12;      // independent gathers in flight per thread

__global__ __launch_bounds__(ST, 8) void k_sstats3(
        const unsigned int* __restrict__ tmp, const int* __restrict__ cur0,
        const int* __restrict__ s1, const int* __restrict__ s2,
        const float* __restrict__ x,
        float* __restrict__ out0, float* __restrict__ stats2,
        int C1, int C2, int nb1) {
    __shared__ int curs[512];
    __shared__ int sorted[CAP];   // 48KB
    int bkt = blockIdx.x;
    int shift, lab0g, lab0loc, nlabs;
    const int* sz; float* outp;
    if (bkt < nb1) {
        shift = 9; lab0g = bkt << 9; lab0loc = lab0g;
        nlabs = min(512, C1 - lab0g); sz = s1; outp = out0;
    } else {
        shift = 7; int lb = (bkt - nb1) << 7; lab0g = C1 + lb; lab0loc = lb;
        nlabs = min(128, C2 - lb); sz = s2; outp = stats2;
    }
    const int lmask = (1 << shift) - 1;
    const int s = cur0[lab0g];
    int count = cur0[lab0g + nlabs] - s;   // cur0[L]=2N set by k_init_bcur
    if (count > CAP) count = CAP;          // guard (never hit)
    for (int j = threadIdx.x; j < nlabs; j += ST) curs[j] = cur0[lab0g + j] - s;
    __syncthreads();
    // LDS counting sort of element ids by label
    for (int j = threadIdx.x; j < count; j += ST) {
        unsigned en = tmp[s + j];
        int lab = (int)(en & (unsigned)lmask);
        int pos = atomicAdd(&curs[lab], 1);
        if (pos < CAP) sorted[pos] = (int)(en >> shift);
    }
    __syncthreads();

    const int c2 = threadIdx.x & 3;   // channel pair: covers channels 2*c2, 2*c2+1
    if (bkt < nb1) {
        // ---- field 1: 4 lanes per label, float2 gather, 12-deep MLP ----
        const int group = threadIdx.x >> 2;        // 0..255
        for (int lab = group; lab < nlabs; lab += (ST >> 2)) {
            int n = sz[lab0loc + lab];
            int start = cur0[lab0g + lab] - s;
            int nn = n;
            if (start >= CAP) nn = 0;
            else if (start + nn > CAP) nn = CAP - start;
            float mn0 = INFINITY, mn1 = INFINITY, mx0 = -INFINITY, mx1 = -INFINITY;
            float sm0 = 0.f, sm1 = 0.f;
            const int nm1 = nn - 1;
            for (int j = 0; j < nn; j += UNR) {
                float2 u[UNR];
                #pragma unroll
                for (int k = 0; k < UNR; ++k) {
                    int jj = j + k;
                    int jc = (jj < nn) ? jj : nm1;   // clamped -> always safe
                    int e = sorted[start + jc];
                    u[k] = *(const float2*)(x + (size_t)e * CH + 2 * c2);
                }
                #pragma unroll
                for (int k = 0; k < UNR; ++k) {
                    bool ok = (j + k) < nn;
                    mn0 = fminf(mn0, ok ? u[k].x : INFINITY);
                    mx0 = fmaxf(mx0, ok ? u[k].x : -INFINITY);
                    sm0 += ok ? u[k].x : 0.f;
                    mn1 = fminf(mn1, ok ? u[k].y : INFINITY);
                    mx1 = fmaxf(mx1, ok ? u[k].y : -INFINITY);
                    sm1 += ok ? u[k].y : 0.f;
                }
            }
            float inv = 1.f / (float)n;
            float* row = outp + (size_t)(lab0loc + lab) * COLS;
            int c = 2 * c2;
            row[c]          = mn0;
            row[c + 1]      = mn1;
            row[8 + c]      = mx0;
            row[8 + c + 1]  = mx1;
            row[16 + c]     = sm0 * inv;
            row[16 + c + 1] = sm1 * inv;
            if (c2 == 0) row[24] = expf(-(float)n) - 0.5f;
        }
    } else {
        // ---- field 2: 8 lanes per label (even/odd element split, shfl merge) ----
        const int half = (threadIdx.x >> 2) & 1;
        const int group = threadIdx.x >> 3;        // 0..127
        for (int lab = group; lab < nlabs; lab += (ST >> 3)) {
            int n = sz[lab0loc + lab];
            int start = cur0[lab0g + lab] - s;
            int nn = n;
            if (start >= CAP) nn = 0;
            else if (start + nn > CAP) nn = CAP - start;
            const int cntH = (nn - half + 1) >> 1;   // elements j with j%2==half
            float mn0 = INFINITY, mn1 = INFINITY, mx0 = -INFINITY, mx1 = -INFINITY;
            float sm0 = 0.f, sm1 = 0.f;
            const int nm1 = nn - 1;
            for (int t = 0; t < cntH; t += UNR) {
                float2 u[UNR];
                #pragma unroll
                for (int k = 0; k < UNR; ++k) {
                    int tt = t + k;
                    int jj = half + 2 * tt;
                    int jc = (tt < cntH) ? jj : nm1;
                    int e = sorted[start + jc];
                    u[k] = *(const float2*)(x + (size_t)e * CH + 2 * c2);
                }
                #pragma unroll
                for (int k = 0; k < UNR; ++k) {
                    bool ok = (t + k) < cntH;
                    mn0 = fminf(mn0, ok ? u[k].x : INFINITY);
                    mx0 = fmaxf(mx0, ok ? u[k].x : -INFINITY);
                    sm0 += ok ? u[k].x : 0.f;
                    mn1 = fminf(mn1, ok ? u[k].y : INFINITY);
                    mx1 = fmaxf(mx1, ok ? u[k].y : -INFINITY);
                    sm1 += ok ? u[k].y : 0.f;
                }
            }
            mn0 = fminf(mn0, __shfl_xor(mn0, 4));
            mn1 = fminf(mn1, __shfl_xor(mn1, 4));
            mx0 = fmaxf(mx0, __shfl_xor(mx0, 4));
            mx1 = fmaxf(mx1, __shfl_xor(mx1, 4));
            sm0 += __shfl_xor(sm0, 4);
            sm1 += __shfl_xor(sm1, 4);
            if (half == 0) {
                float inv = 1.f / (float)n;
                float* row = outp + (size_t)(lab0loc + lab) * COLS;
                int c = 2 * c2;
                row[c]          = mn0;
                row[c + 1]      = mn1;
                row[8 + c]      = mx0;
                row[8 + c + 1]  = mx1;
                row[16 + c]     = sm0 * inv;
                row[16 + c + 1] = sm1 * inv;
                if (c2 == 0) row[24] = expf(-(float)n) - 0.5f;
            }
        }
    }
}

// ---------------- edge gather ----------------
__global__ void k_edges(const int* __restrict__ bounds, const float* __restrict__ stats2,
                        float* __restrict__ out1, float* __restrict__ out2, int C1) {
    int t = blockIdx.x * blockDim.x + threadIdx.x;
    int total = C1 * COLS;
    if (t >= 2 * total) return;
    int half = (t >= total) ? 1 : 0;
    int u = t - half * total;
    int e = u / COLS;
    int k = u - e * COLS;
    int node = bounds[e * 2 + half] - 1;
    float v = stats2[(size_t)node * COLS + k];
    (half ? out2 : out1)[u] = v;
}

extern "C" void kernel_launch(void* const* d_in, const int* in_sizes, int n_in,
                              void* d_out, int out_size, void* d_ws, size_t ws_size,
                              hipStream_t stream) {
    const float* x      = (const float*)d_in[0];
    const int*   m1     = (const int*)d_in[1];
    const int*   m2     = (const int*)d_in[2];
    const int*   bounds = (const int*)d_in[3];
    const int*   s1     = (const int*)d_in[4];
    const int*   s2     = (const int*)d_in[5];
    const int N  = in_sizes[1];
    const int C1 = in_sizes[4];
    const int C2 = in_sizes[5];
    const int L  = C1 + C2;
    const int nb1 = (C1 + 511) >> 9;   // 782
    const int nb2 = (C2 + 127) >> 7;   // 782
    const int nbk = nb1 + nb2;

    char* ws = (char*)d_ws;
    auto take = [&](size_t bytes) {
        char* p = ws;
        ws += (bytes + 255) & ~(size_t)255;
        return p;
    };
    int*   cur0      = (int*)  take((size_t)(L + 1) * 4);
    float* stats2    = (float*)take((size_t)C2 * COLS * 4);
    int*   blockSums = (int*)  take(1024);
    int*   bcur      = (int*)  take((size_t)nbk * 4);

    float* out0 = (float*)d_out;
    float* out1 = out0 + (size_t)C1 * COLS;
    float* out2 = out1 + (size_t)C1 * COLS;
    // tmp (2N uints = 67MB) lives in the out1/out2 region (80MB), consumed by k_sstats3
    unsigned int* tmp = (unsigned int*)out1;

    const int nb = (L + SCAN_B - 1) / SCAN_B;   // 123 (<=256)
    k_block_sums<<<nb, SCAN_T, 0, stream>>>(s1, s2, C1, C2, blockSums);
    k_scan_block_sums<<<1, 256, 0, stream>>>(blockSums, nb);
    k_write_offsets<<<nb, SCAN_T, 0, stream>>>(s1, s2, blockSums, C1, C2, cur0);
    k_init_bcur<<<(nbk + 255) / 256, 256, 0, stream>>>(cur0, bcur, C1, C2, nb1, nb2, 2 * N);

    const int binGrid = (N + BE2 - 1) / BE2;   // 1024
    k_bin2<<<binGrid, BT2, 0, stream>>>(m1, m2, bcur, bcur + nb1, tmp, N);

    k_sstats3<<<nbk, ST, 0, stream>>>(tmp, cur0, s1, s2, x, out0, stats2, C1, C2, nb1);

    int edge_threads = 2 * C1 * COLS;
    k_edges<<<(edge_threads + 255) / 256, 256, 0, stream>>>(bounds, stats2, out1, out2, C1);
}